// Round 7
// baseline (346.607 us; speedup 1.0000x reference)
//
#include <hip/hip_runtime.h>
#include <math.h>

typedef unsigned int u32;
typedef unsigned long long u64;
typedef _Float16 f16;
typedef f16 half8v __attribute__((ext_vector_type(8)));
typedef float f32x4 __attribute__((ext_vector_type(4)));

#define Bc 128
#define Dc 1024
#define Hc 131072
#define Oc 1024
#define Rc 512

#define NBINS 4096
#define NSUB 2
#define CAP 6144

// ws layout in 4-byte units
#define WS_SCORES ((size_t)0)
#define WS_SEL    ((size_t)Bc * Hc)
#define WS_PART   (WS_SEL + (size_t)Bc * Rc)
#define WS_XHI    (WS_PART + (size_t)Bc * 4 * Oc)         // x hi split, 131072 f16
#define WS_XLO    (WS_XHI + (size_t)Bc * Dc / 2)          // x lo split

__device__ __forceinline__ u32 mono_key(float f) {
    u32 u = __float_as_uint(f);
    return (u & 0x80000000u) ? ~u : (u | 0x80000000u);
}

__device__ __forceinline__ void dma16(const void* gsrc, void* ldst) {
    __builtin_amdgcn_global_load_lds(
        (const __attribute__((address_space(1))) unsigned int*)gsrc,
        (__attribute__((address_space(3))) unsigned int*)ldst, 16, 0, 0);
}

// ---------------- K0: split x into f16 hi + scaled-lo, LINEAR layout ----------------
// Elem (row, k) at kt*4096 + row*32 + (k&31), kt = k>>5. DMA-source swizzle in k1.
__global__ __launch_bounds__(512) void kx_split(const float* __restrict__ x,
                                                f16* __restrict__ xhi,
                                                f16* __restrict__ xlo) {
    int c = blockIdx.x * 512 + threadIdx.x;   // 0..16383 chunks of 8
    int row = c >> 7;                         // 0..127
    int kc = c & 127;                         // k-chunk
    const float* src = x + (size_t)row * Dc + kc * 8;
    float4 v0 = *reinterpret_cast<const float4*>(src);
    float4 v1 = *reinterpret_cast<const float4*>(src + 4);
    int dst = (kc >> 2) * 4096 + row * 32 + (kc & 3) * 8;
    half8v h, l;
#pragma unroll
    for (int e = 0; e < 8; ++e) {
        float f = (e < 4) ? reinterpret_cast<const float*>(&v0)[e]
                          : reinterpret_cast<const float*>(&v1)[e - 4];
        f16 hh = (f16)f;
        h[e] = hh;
        l[e] = (f16)((f - (float)hh) * 2048.0f);
    }
    *reinterpret_cast<half8v*>(xhi + dst) = h;
    *reinterpret_cast<half8v*>(xlo + dst) = l;
}

// ---------------- K1: S = x @ Win^T, f16-split MFMA, wave role-split ----------------
// 128x128 tile, BK=32, 512 thr = 8 waves. Waves 0-3: acc1 = hi*hi for quadrant q.
// Waves 4-7: acc2 = hi*lo' + lo'*hi for quadrant q. Single 64-VGPR acc per wave
// -> launch_bounds(512,4) -> 16 waves/CU (2 blocks). S = acc1 + acc2/2048,
// per-accumulator MFMA order identical to R4 -> S bit-identical.
// Buffer (32 KB): Ahi[8K] | Alo[8K] | B fp32 [16K]. dbuf = 64 KB.
// Swizzles (both-sides, free 2-way): A granule lk^((r>>1)&3), B granule g^(c&7).
#define BUFSZ 32768
#define K1_LDS_BYTES (2 * BUFSZ)
__global__ __launch_bounds__(512, 4) void k1_mfma(const float* __restrict__ Win,
                                                  const f16* __restrict__ xhi,
                                                  const f16* __restrict__ xlo,
                                                  float* __restrict__ S) {
    extern __shared__ char k1lds[];
    const int tid = threadIdx.x;
    const int h0 = blockIdx.x * 128;
    const int lane = tid & 63;
    const int wid = tid >> 6;          // 0..7
    const int role = wid >> 2;         // 0 = hi, 1 = cross
    const int q = wid & 3;             // quadrant
    const int wm = q >> 1, wn = q & 1;
    const int lr = lane & 15;
    const int lk = lane >> 4;

    // --- DMA source addressing (per thread), dest linear (rule 21) ---
    // A: thread t -> granule (r = t>>2, gp = t&3), source granule g = gp ^ ((r>>1)&3)
    const int ar = tid >> 2;
    const int agp = tid & 3;
    const int asrc = ar * 32 + ((agp ^ ((ar >> 1) & 3)) << 3);     // f16 units
    // B: thread t -> granules G = t and t+512; (c = G>>3, gp = G&7), g = gp ^ (c&7)
    const int bc0 = tid >> 3, bgp0 = tid & 7;
    const int bc1 = (tid + 512) >> 3, bgp1 = (tid + 512) & 7;
    const size_t bsrc0 = (size_t)(h0 + bc0) * Dc + ((bgp0 ^ (bc0 & 7)) << 2);  // floats
    const size_t bsrc1 = (size_t)(h0 + bc1) * Dc + ((bgp1 ^ (bc1 & 7)) << 2);
    const int dqa = wid * 1024;        // per-wave uniform dest offset (bytes)

#define STAGE(KT, BUF) do {                                                  \
        char* bb_ = k1lds + (BUF) * BUFSZ;                                   \
        dma16(xhi + (KT) * 4096 + asrc, bb_ + 0     + dqa);                  \
        dma16(xlo + (KT) * 4096 + asrc, bb_ + 8192  + dqa);                  \
        dma16(Win + bsrc0 + (KT) * 32,  bb_ + 16384 + dqa);                  \
        dma16(Win + bsrc1 + (KT) * 32,  bb_ + 24576 + dqa);                  \
    } while (0)

    f32x4 acc[4][4];
#pragma unroll
    for (int i = 0; i < 4; ++i)
#pragma unroll
        for (int j = 0; j < 4; ++j) acc[i][j] = (f32x4){0.f, 0.f, 0.f, 0.f};

    STAGE(0, 0);
    __syncthreads();

    for (int ks = 0; ks < 32; ++ks) {
        if (ks < 31) STAGE(ks + 1, (ks + 1) & 1);
        const char* cb = k1lds + (ks & 1) * BUFSZ;
        const f16* Ahi = (const f16*)cb;
        const f16* Alo = (const f16*)(cb + 8192);
        const float* Bf = (const float*)(cb + 16384);

        if (role == 0) {
            // hi waves: acc += Ahi * Bhi
#pragma unroll
            for (int j = 0; j < 4; ++j) {
                int c = wn * 64 + j * 16 + lr;
                float4 p0 = *reinterpret_cast<const float4*>(Bf + c * 32 + (((2 * lk) ^ (c & 7)) << 2));
                float4 p1 = *reinterpret_cast<const float4*>(Bf + c * 32 + (((2 * lk + 1) ^ (c & 7)) << 2));
                half8v bh;
#pragma unroll
                for (int e = 0; e < 4; ++e) {
                    bh[e]     = (f16)reinterpret_cast<const float*>(&p0)[e];
                    bh[e + 4] = (f16)reinterpret_cast<const float*>(&p1)[e];
                }
#pragma unroll
                for (int i = 0; i < 4; ++i) {
                    int r = wm * 64 + i * 16 + lr;
                    half8v a = *reinterpret_cast<const half8v*>(Ahi + r * 32 + ((lk ^ ((r >> 1) & 3)) << 3));
                    acc[i][j] = __builtin_amdgcn_mfma_f32_16x16x32_f16(a, bh, acc[i][j], 0, 0, 0);
                }
            }
        } else {
            // cross waves: acc += Ahi * Blo  then  Alo * Bhi (per-acc order = R4)
#pragma unroll
            for (int j = 0; j < 4; ++j) {
                int c = wn * 64 + j * 16 + lr;
                float4 p0 = *reinterpret_cast<const float4*>(Bf + c * 32 + (((2 * lk) ^ (c & 7)) << 2));
                float4 p1 = *reinterpret_cast<const float4*>(Bf + c * 32 + (((2 * lk + 1) ^ (c & 7)) << 2));
                half8v bh, bl;
#pragma unroll
                for (int e = 0; e < 4; ++e) {
                    float f = reinterpret_cast<const float*>(&p0)[e];
                    f16 hh = (f16)f;
                    bh[e] = hh; bl[e] = (f16)((f - (float)hh) * 2048.0f);
                    f = reinterpret_cast<const float*>(&p1)[e];
                    hh = (f16)f;
                    bh[e + 4] = hh; bl[e + 4] = (f16)((f - (float)hh) * 2048.0f);
                }
                half8v ah[4], al[4];
#pragma unroll
                for (int i = 0; i < 4; ++i) {
                    int r = wm * 64 + i * 16 + lr;
                    int ad = r * 32 + ((lk ^ ((r >> 1) & 3)) << 3);
                    ah[i] = *reinterpret_cast<const half8v*>(Ahi + ad);
                    al[i] = *reinterpret_cast<const half8v*>(Alo + ad);
                }
#pragma unroll
                for (int i = 0; i < 4; ++i)
                    acc[i][j] = __builtin_amdgcn_mfma_f32_16x16x32_f16(ah[i], bl, acc[i][j], 0, 0, 0);
#pragma unroll
                for (int i = 0; i < 4; ++i)
                    acc[i][j] = __builtin_amdgcn_mfma_f32_16x16x32_f16(al[i], bh, acc[i][j], 0, 0, 0);
            }
        }
        __syncthreads();   // DMAs for ks+1 drained (implicit vmcnt0) + all reads of cb done
    }
#undef STAGE

    // epilogue: cross waves deposit acc2; hi waves combine and write S.
    float* cmb = (float*)k1lds;        // 64 KB, quadrant q at q*4096 floats
    if (role == 1) {
#pragma unroll
        for (int i = 0; i < 4; ++i)
#pragma unroll
            for (int j = 0; j < 4; ++j)
#pragma unroll
                for (int r = 0; r < 4; ++r)
                    cmb[q * 4096 + (i * 16 + lk * 4 + r) * 64 + (j * 16 + lr)] = acc[i][j][r];
    }
    __syncthreads();
    if (role == 0) {
#pragma unroll
        for (int i = 0; i < 4; ++i)
#pragma unroll
            for (int j = 0; j < 4; ++j)
#pragma unroll
                for (int r = 0; r < 4; ++r) {
                    int row = wm * 64 + i * 16 + lk * 4 + r;
                    int col = h0 + wn * 64 + j * 16 + lr;
                    float cr = cmb[q * 4096 + (i * 16 + lk * 4 + r) * 64 + (j * 16 + lr)];
                    S[(size_t)row * Hc + col] = acc[i][j][r] + cr * (1.0f / 2048.0f);
                }
    }
}

// ---------------- K2: fused hist + threshold + select (one block per row) ----------------
#define K2_LDS_BYTES ((NSUB * NBINS) * 4 + Rc * 8 + CAP * 8)
__global__ __launch_bounds__(1024) void k2_select(const float* __restrict__ S,
                                                  u32* __restrict__ selidx) {
    extern __shared__ u32 dyn[];
    u32* lh  = dyn;                               // NSUB*NBINS
    u64* top = (u64*)(dyn + NSUB * NBINS);        // 512
    u64* cand = (u64*)(dyn + NSUB * NBINS + Rc * 2);  // CAP
    __shared__ u32 csum[64];
    __shared__ u32 s_bint, s_need, cnt_top, cnt_cand;

    const int b = blockIdx.x;
    const int tid = threadIdx.x;
    for (int i = tid; i < NSUB * NBINS; i += 1024) lh[i] = 0;
    if (tid == 0) { cnt_top = 0; cnt_cand = 0; }
    __syncthreads();

    const float4* row4 = reinterpret_cast<const float4*>(S + (size_t)b * Hc);
    const int sub = (tid & (NSUB - 1)) * NBINS;
    for (int it = 0; it < Hc / 4096; ++it) {
        float4 v = row4[tid + it * 1024];
#pragma unroll
        for (int e = 0; e < 4; ++e) {
            u32 bin = mono_key(reinterpret_cast<const float*>(&v)[e]) >> 20;
            atomicAdd(&lh[sub + bin], 1u);
        }
    }
    __syncthreads();
    for (int i = tid; i < NBINS; i += 1024) lh[i] += lh[NBINS + i];
    __syncthreads();
    if (tid < 64) {
        u32 s = 0;
        for (int j = 0; j < 64; ++j) s += lh[tid * 64 + j];
        csum[tid] = s;
    }
    __syncthreads();
    if (tid == 0) {
        u32 cum = 0;
        int c;
        for (c = 63; c >= 0; --c) {
            if (cum + csum[c] >= (u32)Rc) break;
            cum += csum[c];
        }
        int bin_t = 0; u32 above = 0;
        for (int j = 63; j >= 0; --j) {
            int bin = c * 64 + j;
            if (cum + lh[bin] >= (u32)Rc) { bin_t = bin; above = cum; break; }
            cum += lh[bin];
        }
        s_bint = (u32)bin_t;
        s_need = (u32)Rc - above;
    }
    __syncthreads();
    const u32 bin_t = s_bint;
    const u32 need  = s_need;
    for (int it = 0; it < Hc / 4096; ++it) {
        float4 v = row4[tid + it * 1024];
        int i0 = (tid + it * 1024) * 4;
#pragma unroll
        for (int e = 0; e < 4; ++e) {
            u32 u = mono_key(reinterpret_cast<const float*>(&v)[e]);
            u32 bin = u >> 20;
            if (bin > bin_t) {
                u32 p = atomicAdd(&cnt_top, 1u);
                top[p] = ((u64)u << 32) | (u64)(0xFFFFFFFFu - (u32)(i0 + e));
            } else if (bin == bin_t) {
                u32 p = atomicAdd(&cnt_cand, 1u);
                if (p < CAP) cand[p] = ((u64)u << 32) | (u64)(0xFFFFFFFFu - (u32)(i0 + e));
            }
        }
    }
    __syncthreads();
    const int ntop = (int)cnt_top;
    const int nc   = (int)(cnt_cand < (u32)CAP ? cnt_cand : (u32)CAP);
    u32* sel = selidx + (size_t)b * Rc;
    for (int j = tid; j < ntop; j += 1024) {
        u64 my = top[j];
        u32 r = 0;
        for (int k = 0; k < ntop; ++k) r += (top[k] > my) ? 1u : 0u;
        sel[r] = 0xFFFFFFFFu - (u32)(my & 0xFFFFFFFFu);
    }
    for (int j = tid; j < nc; j += 1024) {
        u64 my = cand[j];
        u32 r = 0;
        for (int k = 0; k < nc; ++k) r += (cand[k] > my) ? 1u : 0u;
        if (r < need) sel[ntop + r] = 0xFFFFFFFFu - (u32)(my & 0xFFFFFFFFu);
    }
}

// ---------------- K3: partial[b][ch][o] = sum over 128 selected rows ----------------
__global__ __launch_bounds__(256) void k3_gather(const float* __restrict__ S,
                                                 const float* __restrict__ Wout,
                                                 const u32* __restrict__ selidx,
                                                 float* __restrict__ part) {
    __shared__ float g[128];
    __shared__ u32 il[128];
    const int b  = blockIdx.x >> 2;
    const int ch = blockIdx.x & 3;
    const int tid = threadIdx.x;
    if (tid < 128) {
        u32 idx = selidx[(size_t)b * Rc + ch * 128 + tid];
        il[tid] = idx;
        float s = S[(size_t)b * Hc + idx];
        g[tid] = 0.5f * s * (1.0f + erff(s * 0.70710678118654752f));
    }
    __syncthreads();
    float4 acc = make_float4(0.f, 0.f, 0.f, 0.f);
    const int o0 = tid * 4;
#pragma unroll 4
    for (int j = 0; j < 128; ++j) {
        float w = g[j];
        float4 v = *reinterpret_cast<const float4*>(&Wout[(size_t)il[j] * Oc + o0]);
        acc.x = fmaf(w, v.x, acc.x);
        acc.y = fmaf(w, v.y, acc.y);
        acc.z = fmaf(w, v.z, acc.z);
        acc.w = fmaf(w, v.w, acc.w);
    }
    *reinterpret_cast<float4*>(&part[((size_t)b * 4 + ch) * Oc + o0]) = acc;
}

// ---------------- K4: reduce 4 partials -> out ----------------
__global__ __launch_bounds__(256) void k4_reduce(const float* __restrict__ part,
                                                 float* __restrict__ out) {
    const int b = blockIdx.x;
    const int o0 = threadIdx.x * 4;
    float4 a = *reinterpret_cast<const float4*>(&part[((size_t)b * 4 + 0) * Oc + o0]);
    float4 c1 = *reinterpret_cast<const float4*>(&part[((size_t)b * 4 + 1) * Oc + o0]);
    float4 c2 = *reinterpret_cast<const float4*>(&part[((size_t)b * 4 + 2) * Oc + o0]);
    float4 c3 = *reinterpret_cast<const float4*>(&part[((size_t)b * 4 + 3) * Oc + o0]);
    a.x += c1.x + c2.x + c3.x;
    a.y += c1.y + c2.y + c3.y;
    a.z += c1.z + c2.z + c3.z;
    a.w += c1.w + c2.w + c3.w;
    *reinterpret_cast<float4*>(&out[(size_t)b * Oc + o0]) = a;
}

extern "C" void kernel_launch(void* const* d_in, const int* in_sizes, int n_in,
                              void* d_out, int out_size, void* d_ws, size_t ws_size,
                              hipStream_t stream) {
    (void)in_sizes; (void)n_in; (void)out_size; (void)ws_size;
    const float* x    = (const float*)d_in[0];
    const float* Win  = (const float*)d_in[1];
    const float* Wout = (const float*)d_in[2];
    float* out = (float*)d_out;

    float* S    = (float*)d_ws + WS_SCORES;
    u32*   sel  = (u32*)d_ws + WS_SEL;
    float* part = (float*)d_ws + WS_PART;
    f16*   xhi  = (f16*)((u32*)d_ws + WS_XHI);
    f16*   xlo  = (f16*)((u32*)d_ws + WS_XLO);

    static bool attr_set = false;
    if (!attr_set) {
        hipFuncSetAttribute((const void*)k2_select,
                            hipFuncAttributeMaxDynamicSharedMemorySize, K2_LDS_BYTES);
        hipFuncSetAttribute((const void*)k1_mfma,
                            hipFuncAttributeMaxDynamicSharedMemorySize, K1_LDS_BYTES);
        attr_set = true;
    }

    kx_split<<<32, 512, 0, stream>>>(x, xhi, xlo);
    k1_mfma<<<Hc / 128, 512, K1_LDS_BYTES, stream>>>(Win, xhi, xlo, S);
    k2_select<<<Bc, 1024, K2_LDS_BYTES, stream>>>(S, sel);
    k3_gather<<<Bc * 4, 256, 0, stream>>>(S, Wout, sel, part);
    k4_reduce<<<Bc, 256, 0, stream>>>(part, out);
}

// Round 8
// 310.000 us; speedup vs baseline: 1.1181x; 1.1181x over previous
//
#include <hip/hip_runtime.h>
#include <math.h>

typedef unsigned int u32;
typedef unsigned long long u64;
typedef _Float16 f16;
typedef f16 half8v __attribute__((ext_vector_type(8)));
typedef f16 half4v __attribute__((ext_vector_type(4)));
typedef float f32x4 __attribute__((ext_vector_type(4)));

#define Bc 128
#define Dc 1024
#define Hc 131072
#define Oc 1024
#define Rc 512

#define NBINS 4096
#define NSUB 2
#define CAP 6144

// ws layout in 4-byte units
#define WS_SCORES ((size_t)0)
#define WS_SEL    ((size_t)Bc * Hc)
#define WS_PART   (WS_SEL + (size_t)Bc * Rc)
#define WS_XHI    (WS_PART + (size_t)Bc * 4 * Oc)         // x hi split, 131072 f16
#define WS_XLO    (WS_XHI + (size_t)Bc * Dc / 2)          // x lo split

__device__ __forceinline__ u32 mono_key(float f) {
    u32 u = __float_as_uint(f);
    return (u & 0x80000000u) ? ~u : (u | 0x80000000u);
}

__device__ __forceinline__ void dma16(const void* gsrc, void* ldst) {
    __builtin_amdgcn_global_load_lds(
        (const __attribute__((address_space(1))) unsigned int*)gsrc,
        (__attribute__((address_space(3))) unsigned int*)ldst, 16, 0, 0);
}

// ---------------- K0: split x into f16 hi + scaled-lo, LINEAR layout ----------------
// Elem (row, k) at kt*4096 + row*32 + (k&31), kt = k>>5. DMA-source swizzle in k1.
__global__ __launch_bounds__(512) void kx_split(const float* __restrict__ x,
                                                f16* __restrict__ xhi,
                                                f16* __restrict__ xlo) {
    int c = blockIdx.x * 512 + threadIdx.x;   // 0..16383 chunks of 8
    int row = c >> 7;                         // 0..127
    int kc = c & 127;                         // k-chunk
    const float* src = x + (size_t)row * Dc + kc * 8;
    float4 v0 = *reinterpret_cast<const float4*>(src);
    float4 v1 = *reinterpret_cast<const float4*>(src + 4);
    int dst = (kc >> 2) * 4096 + row * 32 + (kc & 3) * 8;
    half8v h, l;
#pragma unroll
    for (int e = 0; e < 8; ++e) {
        float f = (e < 4) ? reinterpret_cast<const float*>(&v0)[e]
                          : reinterpret_cast<const float*>(&v1)[e - 4];
        f16 hh = (f16)f;
        h[e] = hh;
        l[e] = (f16)((f - (float)hh) * 2048.0f);
    }
    *reinterpret_cast<half8v*>(xhi + dst) = h;
    *reinterpret_cast<half8v*>(xlo + dst) = l;
}

// ---------------- K1: S = x @ Win^T, f16-split MFMA, occupancy-first ----------------
// Tile 128b x 32h, BK=32, 256 thr = 4 waves stacked along b; wave = 32x32 out
// (2m x 2n frags, 12 MFMA/step). acc1+acc2 = 32 VGPR -> total ~90 -> 16 waves/CU.
// Buffer 20 KB: Ahi[8K] | Alo[8K] | Bhi[2K] | Blo[2K]; dbuf 40 KB -> 4 blocks/CU.
// A staged via global_load_lds (source-swizzled, 2-way-free: granule lk^((r>>1)&3));
// B reg-staged fp32 -> hi/lo f16 -> ds_write (read swizzle lk^((c>>1)&3), 2-way-free).
// Per-acc MFMA order identical to R4 -> S bit-identical -> selection unchanged.
#define BUFSZ 20480
__global__ __launch_bounds__(256, 4) void k1_mfma(const float* __restrict__ Win,
                                                  const f16* __restrict__ xhi,
                                                  const f16* __restrict__ xlo,
                                                  float* __restrict__ S) {
    __shared__ char k1lds[2 * BUFSZ];   // 40 KB
    const int tid = threadIdx.x;
    const int h0 = blockIdx.x * 32;
    const int lane = tid & 63;
    const int wid = tid >> 6;          // 0..3, owns rows wid*32..wid*32+31
    const int lr = lane & 15;
    const int lk = lane >> 4;          // k-octet

    // --- A DMA source offsets (dest linear, swizzle folded into source; rule 21) ---
    // storage granule G=(r, gp) holds logical granule gp ^ ((r>>1)&3)
    const int ar0 = tid >> 2,  agp0 = tid & 3;                    // issue 0: G = tid
    const int ar1 = (tid + 256) >> 2, agp1 = (tid + 256) & 3;     // issue 1: G = tid+256
    const int asrc0 = ar0 * 32 + ((agp0 ^ ((ar0 >> 1) & 3)) << 3);  // f16 units
    const int asrc1 = ar1 * 32 + ((agp1 ^ ((ar1 >> 1) & 3)) << 3);
    const int dq = wid * 1024;         // wave-uniform dest offset (bytes) per issue

    // --- B staging: thread t -> (col = t>>3, k-quad g = t&7), one float4 ---
    const int bcol = tid >> 3;
    const int bg = tid & 7;
    const float* bsrc = Win + (size_t)(h0 + bcol) * Dc + bg * 4;
    // dest: k-quad kk stored at 16B-granule (kk>>1)^((col>>1)&3), half (kk&1)
    const int bwoff = bcol * 64 + (((bg >> 1) ^ ((bcol >> 1) & 3)) << 4) + ((bg & 1) << 3);

#define STAGE_A(KT, BUF) do {                                                \
        char* bb_ = k1lds + (BUF) * BUFSZ;                                   \
        dma16(xhi + (KT) * 4096 + asrc0, bb_ + 0    + dq);                   \
        dma16(xhi + (KT) * 4096 + asrc1, bb_ + 4096 + dq);                   \
        dma16(xlo + (KT) * 4096 + asrc0, bb_ + 8192 + dq);                   \
        dma16(xlo + (KT) * 4096 + asrc1, bb_ + 12288 + dq);                  \
    } while (0)

    f32x4 acc1[2][2], acc2[2][2];
#pragma unroll
    for (int i = 0; i < 2; ++i)
#pragma unroll
        for (int j = 0; j < 2; ++j) {
            acc1[i][j] = (f32x4){0.f, 0.f, 0.f, 0.f};
            acc2[i][j] = (f32x4){0.f, 0.f, 0.f, 0.f};
        }

    // prologue: stage ks=0
    {
        STAGE_A(0, 0);
        float4 q = *reinterpret_cast<const float4*>(bsrc);
        half4v bh, bl;
#pragma unroll
        for (int e = 0; e < 4; ++e) {
            float f = reinterpret_cast<const float*>(&q)[e];
            f16 hh = (f16)f;
            bh[e] = hh; bl[e] = (f16)((f - (float)hh) * 2048.0f);
        }
        char* L = k1lds;
        *reinterpret_cast<half4v*>(L + 16384 + bwoff) = bh;
        *reinterpret_cast<half4v*>(L + 18432 + bwoff) = bl;
    }
    __syncthreads();

    for (int ks = 0; ks < 32; ++ks) {
        char* cb = k1lds + (ks & 1) * BUFSZ;
        char* nb = k1lds + ((ks & 1) ^ 1) * BUFSZ;
        const bool pf = (ks < 31);
        float4 q;
        if (pf) {
            q = *reinterpret_cast<const float4*>(bsrc + (ks + 1) * 32);  // issue early
            STAGE_A(ks + 1, (ks + 1) & 1);
        }
        const f16* Ahi = (const f16*)cb;
        const f16* Alo = (const f16*)(cb + 8192);
        const f16* Bhi = (const f16*)(cb + 16384);
        const f16* Blo = (const f16*)(cb + 18432);

        half8v afh[2], afl[2], bfh[2], bfl[2];
#pragma unroll
        for (int i = 0; i < 2; ++i) {
            int r = wid * 32 + i * 16 + lr;
            int ad = r * 32 + ((lk ^ ((r >> 1) & 3)) << 3);
            afh[i] = *reinterpret_cast<const half8v*>(Ahi + ad);
            afl[i] = *reinterpret_cast<const half8v*>(Alo + ad);
        }
#pragma unroll
        for (int j = 0; j < 2; ++j) {
            int c = j * 16 + lr;
            int bd = c * 32 + ((lk ^ ((c >> 1) & 3)) << 3);
            bfh[j] = *reinterpret_cast<const half8v*>(Bhi + bd);
            bfl[j] = *reinterpret_cast<const half8v*>(Blo + bd);
        }
#pragma unroll
        for (int j = 0; j < 2; ++j)
#pragma unroll
            for (int i = 0; i < 2; ++i) {
                acc1[i][j] = __builtin_amdgcn_mfma_f32_16x16x32_f16(afh[i], bfh[j], acc1[i][j], 0, 0, 0);
                acc2[i][j] = __builtin_amdgcn_mfma_f32_16x16x32_f16(afh[i], bfl[j], acc2[i][j], 0, 0, 0);
                acc2[i][j] = __builtin_amdgcn_mfma_f32_16x16x32_f16(afl[i], bfh[j], acc2[i][j], 0, 0, 0);
            }
        if (pf) {
            half4v bh, bl;
#pragma unroll
            for (int e = 0; e < 4; ++e) {
                float f = reinterpret_cast<const float*>(&q)[e];
                f16 hh = (f16)f;
                bh[e] = hh; bl[e] = (f16)((f - (float)hh) * 2048.0f);
            }
            *reinterpret_cast<half4v*>(nb + 16384 + bwoff) = bh;
            *reinterpret_cast<half4v*>(nb + 18432 + bwoff) = bl;
        }
        __syncthreads();
    }
#undef STAGE_A

    // epilogue: C/D layout col=lane&15, row=(lane>>4)*4+rr  [m89-verified]
#pragma unroll
    for (int i = 0; i < 2; ++i)
#pragma unroll
        for (int j = 0; j < 2; ++j)
#pragma unroll
            for (int rr = 0; rr < 4; ++rr) {
                int row = wid * 32 + i * 16 + lk * 4 + rr;
                int col = h0 + j * 16 + lr;
                S[(size_t)row * Hc + col] = acc1[i][j][rr] + acc2[i][j][rr] * (1.0f / 2048.0f);
            }
}

// ---------------- K2: fused hist + threshold + select (one block per row) ----------------
#define K2_LDS_BYTES ((NSUB * NBINS) * 4 + Rc * 8 + CAP * 8)
__global__ __launch_bounds__(1024) void k2_select(const float* __restrict__ S,
                                                  u32* __restrict__ selidx) {
    extern __shared__ u32 dyn[];
    u32* lh  = dyn;                               // NSUB*NBINS
    u64* top = (u64*)(dyn + NSUB * NBINS);        // 512
    u64* cand = (u64*)(dyn + NSUB * NBINS + Rc * 2);  // CAP
    __shared__ u32 csum[64];
    __shared__ u32 s_bint, s_need, cnt_top, cnt_cand;

    const int b = blockIdx.x;
    const int tid = threadIdx.x;
    for (int i = tid; i < NSUB * NBINS; i += 1024) lh[i] = 0;
    if (tid == 0) { cnt_top = 0; cnt_cand = 0; }
    __syncthreads();

    const float4* row4 = reinterpret_cast<const float4*>(S + (size_t)b * Hc);
    const int sub = (tid & (NSUB - 1)) * NBINS;
    for (int it = 0; it < Hc / 4096; ++it) {
        float4 v = row4[tid + it * 1024];
#pragma unroll
        for (int e = 0; e < 4; ++e) {
            u32 bin = mono_key(reinterpret_cast<const float*>(&v)[e]) >> 20;
            atomicAdd(&lh[sub + bin], 1u);
        }
    }
    __syncthreads();
    for (int i = tid; i < NBINS; i += 1024) lh[i] += lh[NBINS + i];
    __syncthreads();
    if (tid < 64) {
        u32 s = 0;
        for (int j = 0; j < 64; ++j) s += lh[tid * 64 + j];
        csum[tid] = s;
    }
    __syncthreads();
    if (tid == 0) {
        u32 cum = 0;
        int c;
        for (c = 63; c >= 0; --c) {
            if (cum + csum[c] >= (u32)Rc) break;
            cum += csum[c];
        }
        int bin_t = 0; u32 above = 0;
        for (int j = 63; j >= 0; --j) {
            int bin = c * 64 + j;
            if (cum + lh[bin] >= (u32)Rc) { bin_t = bin; above = cum; break; }
            cum += lh[bin];
        }
        s_bint = (u32)bin_t;
        s_need = (u32)Rc - above;
    }
    __syncthreads();
    const u32 bin_t = s_bint;
    const u32 need  = s_need;
    for (int it = 0; it < Hc / 4096; ++it) {
        float4 v = row4[tid + it * 1024];
        int i0 = (tid + it * 1024) * 4;
#pragma unroll
        for (int e = 0; e < 4; ++e) {
            u32 u = mono_key(reinterpret_cast<const float*>(&v)[e]);
            u32 bin = u >> 20;
            if (bin > bin_t) {
                u32 p = atomicAdd(&cnt_top, 1u);
                top[p] = ((u64)u << 32) | (u64)(0xFFFFFFFFu - (u32)(i0 + e));
            } else if (bin == bin_t) {
                u32 p = atomicAdd(&cnt_cand, 1u);
                if (p < CAP) cand[p] = ((u64)u << 32) | (u64)(0xFFFFFFFFu - (u32)(i0 + e));
            }
        }
    }
    __syncthreads();
    const int ntop = (int)cnt_top;
    const int nc   = (int)(cnt_cand < (u32)CAP ? cnt_cand : (u32)CAP);
    u32* sel = selidx + (size_t)b * Rc;
    for (int j = tid; j < ntop; j += 1024) {
        u64 my = top[j];
        u32 r = 0;
        for (int k = 0; k < ntop; ++k) r += (top[k] > my) ? 1u : 0u;
        sel[r] = 0xFFFFFFFFu - (u32)(my & 0xFFFFFFFFu);
    }
    for (int j = tid; j < nc; j += 1024) {
        u64 my = cand[j];
        u32 r = 0;
        for (int k = 0; k < nc; ++k) r += (cand[k] > my) ? 1u : 0u;
        if (r < need) sel[ntop + r] = 0xFFFFFFFFu - (u32)(my & 0xFFFFFFFFu);
    }
}

// ---------------- K3: partial[b][ch][o] = sum over 128 selected rows ----------------
__global__ __launch_bounds__(256) void k3_gather(const float* __restrict__ S,
                                                 const float* __restrict__ Wout,
                                                 const u32* __restrict__ selidx,
                                                 float* __restrict__ part) {
    __shared__ float g[128];
    __shared__ u32 il[128];
    const int b  = blockIdx.x >> 2;
    const int ch = blockIdx.x & 3;
    const int tid = threadIdx.x;
    if (tid < 128) {
        u32 idx = selidx[(size_t)b * Rc + ch * 128 + tid];
        il[tid] = idx;
        float s = S[(size_t)b * Hc + idx];
        g[tid] = 0.5f * s * (1.0f + erff(s * 0.70710678118654752f));
    }
    __syncthreads();
    float4 acc = make_float4(0.f, 0.f, 0.f, 0.f);
    const int o0 = tid * 4;
#pragma unroll 4
    for (int j = 0; j < 128; ++j) {
        float w = g[j];
        float4 v = *reinterpret_cast<const float4*>(&Wout[(size_t)il[j] * Oc + o0]);
        acc.x = fmaf(w, v.x, acc.x);
        acc.y = fmaf(w, v.y, acc.y);
        acc.z = fmaf(w, v.z, acc.z);
        acc.w = fmaf(w, v.w, acc.w);
    }
    *reinterpret_cast<float4*>(&part[((size_t)b * 4 + ch) * Oc + o0]) = acc;
}

// ---------------- K4: reduce 4 partials -> out ----------------
__global__ __launch_bounds__(256) void k4_reduce(const float* __restrict__ part,
                                                 float* __restrict__ out) {
    const int b = blockIdx.x;
    const int o0 = threadIdx.x * 4;
    float4 a = *reinterpret_cast<const float4*>(&part[((size_t)b * 4 + 0) * Oc + o0]);
    float4 c1 = *reinterpret_cast<const float4*>(&part[((size_t)b * 4 + 1) * Oc + o0]);
    float4 c2 = *reinterpret_cast<const float4*>(&part[((size_t)b * 4 + 2) * Oc + o0]);
    float4 c3 = *reinterpret_cast<const float4*>(&part[((size_t)b * 4 + 3) * Oc + o0]);
    a.x += c1.x + c2.x + c3.x;
    a.y += c1.y + c2.y + c3.y;
    a.z += c1.z + c2.z + c3.z;
    a.w += c1.w + c2.w + c3.w;
    *reinterpret_cast<float4*>(&out[(size_t)b * Oc + o0]) = a;
}

extern "C" void kernel_launch(void* const* d_in, const int* in_sizes, int n_in,
                              void* d_out, int out_size, void* d_ws, size_t ws_size,
                              hipStream_t stream) {
    (void)in_sizes; (void)n_in; (void)out_size; (void)ws_size;
    const float* x    = (const float*)d_in[0];
    const float* Win  = (const float*)d_in[1];
    const float* Wout = (const float*)d_in[2];
    float* out = (float*)d_out;

    float* S    = (float*)d_ws + WS_SCORES;
    u32*   sel  = (u32*)d_ws + WS_SEL;
    float* part = (float*)d_ws + WS_PART;
    f16*   xhi  = (f16*)((u32*)d_ws + WS_XHI);
    f16*   xlo  = (f16*)((u32*)d_ws + WS_XLO);

    static bool attr_set = false;
    if (!attr_set) {
        hipFuncSetAttribute((const void*)k2_select,
                            hipFuncAttributeMaxDynamicSharedMemorySize, K2_LDS_BYTES);
        attr_set = true;
    }

    kx_split<<<32, 512, 0, stream>>>(x, xhi, xlo);
    k1_mfma<<<Hc / 32, 256, 0, stream>>>(Win, xhi, xlo, S);
    k2_select<<<Bc, 1024, K2_LDS_BYTES, stream>>>(S, sel);
    k3_gather<<<Bc * 4, 256, 0, stream>>>(S, Wout, sel, part);
    k4_reduce<<<Bc, 256, 0, stream>>>(part, out);
}